// Round 7
// baseline (306.166 us; speedup 1.0000x reference)
//
#include <hip/hip_runtime.h>
#include <math.h>

#define H 51
#define TSEEN 256
#define FUT 16
#define TTOT (TSEEN + FUT)
#define NB 8
#define THREADS 512
#define NWAVE 8
#define UPW 7                 // units per wave (8*7=56 >= 51)
#define NBLOCKS (2048 / NB)   // 256 blocks -> 1/CU, 8 waves = 2 waves/SIMD

typedef _Float16 f16;
typedef _Float16 f16x8 __attribute__((ext_vector_type(8)));
typedef float f32x4 __attribute__((ext_vector_type(4)));

__device__ __forceinline__ float fast_rcp(float x) { return __builtin_amdgcn_rcpf(x); }
// sigmoid/tanh via v_exp; both saturate cleanly (rcp(inf)=0)
__device__ __forceinline__ float sigf(float x) {
  return fast_rcp(1.f + __expf(-x));
}
__device__ __forceinline__ float tanhf_(float x) {
  return fmaf(2.f, fast_rcp(1.f + __expf(-2.f * x)), -1.f);
}

#define MFMA __builtin_amdgcn_mfma_f32_16x16x32_f16

__launch_bounds__(THREADS, 2)
__global__ void lstm2_kernel(const float* __restrict__ inp,
                             const float* __restrict__ Wih1,
                             const float* __restrict__ bih1,
                             const float* __restrict__ Whh1,
                             const float* __restrict__ bhh1,
                             const float* __restrict__ Wih2,
                             const float* __restrict__ bih2,
                             const float* __restrict__ Whh2,
                             const float* __restrict__ bhh2,
                             const float* __restrict__ Wlin,
                             const float* __restrict__ blin,
                             float* __restrict__ out)
{
  // B-operand buffers in MFMA fragment layout:
  // [parity][hi/lo][ktile][lane][j]; logical (k,n): lane = n + 16*((k&31)>>3), j = k&7
  __shared__ __align__(16) f16 Bh1[2][2][2][64][8];
  __shared__ __align__(16) f16 Bh2[2][2][2][64][8];
  __shared__ __align__(16) float xs[TSEEN][NB];
  __shared__ float parts[2][NWAVE][NB];

  const int tid  = threadIdx.x;
  const int wv   = tid >> 6;
  const int lane = tid & 63;
  const int l15  = lane & 15;
  const int g4   = lane >> 4;
  const int bq   = l15 & 7;            // this lane's batch for the cell phase
  const bool mhi = (l15 & 8) != 0;     // takes the m=1 accumulator via xor-8
  const int baseb = blockIdx.x * NB;

  // ---- zero B buffers (pad slots stay 0 forever) ----
  {
    f16* b1 = &Bh1[0][0][0][0][0];
    f16* b2 = &Bh2[0][0][0][0][0];
    for (int i = tid; i < 2 * 2 * 2 * 64 * 8; i += THREADS) {
      b1[i] = (f16)0.f; b2[i] = (f16)0.f;
    }
  }
  // ---- stage inputs (coalesced per batch row) ----
  for (int i = tid; i < NB * TSEEN; i += THREADS) {
    int b = i >> 8, t = i & 255;
    xs[t][b] = inp[(size_t)(baseb + b) * TSEEN + t];
  }
  if (tid < 2 * NWAVE * NB) (&parts[0][0][0])[tid] = 0.f;

  // ---- A fragments (f16), virtual row v = 4*unit_slot + gate; 2 M-tiles/wave ----
  f16x8 A1[2][2], A2[2][2], A3[2][2];
  #pragma unroll
  for (int m = 0; m < 2; ++m) {
    const int slotA = 4 * m + (l15 >> 2);
    const int uA = UPW * wv + slotA;
    const int gA = l15 & 3;
    const bool vA = (slotA < UPW) && (uA < H);
    const int row = gA * H + (vA ? uA : 0);
    #pragma unroll
    for (int kt = 0; kt < 2; ++kt) {
      #pragma unroll
      for (int j = 0; j < 8; ++j) {
        const int k = 32 * kt + 8 * g4 + j;
        float w1 = 0.f, w2 = 0.f, w3 = 0.f;
        if (vA) {
          if (k < H) {
            w1 = Whh1[row * H + k];
            w2 = Wih2[row * H + k];
            w3 = Whh2[row * H + k];
          } else if (k == H) {
            w1 = Wih1[row];        // x folded in as k-slot 51 (layer 1 only)
          }
        }
        A1[m][kt][j] = (f16)w1;
        A2[m][kt][j] = (f16)w2;
        A3[m][kt][j] = (f16)w3;
      }
    }
  }

  // ---- bias C-in fragments (C layout: unit_slot = 4m+g4, gate = reg) ----
  f32x4 bias1[2], bias2[2];
  #pragma unroll
  for (int m = 0; m < 2; ++m) {
    const int ulC = 4 * m + g4;
    const int u = UPW * wv + ulC;
    const bool v = (ulC < UPW) && (u < H);
    #pragma unroll
    for (int r = 0; r < 4; ++r) {
      const int rr = r * H + (v ? u : 0);
      bias1[m][r] = v ? (bih1[rr] + bhh1[rr]) : 0.f;
      bias2[m][r] = v ? (bih2[rr] + bhh2[rr]) : 0.f;
    }
  }

  // ---- this lane's cell: unit slot (mhi? 4:0)+g4, batch bq ----
  const int slotC = (mhi ? 4 : 0) + g4;
  const int uC0 = UPW * wv + slotC;
  const bool vC = (slotC < UPW) && (uC0 < H);
  const int uC = vC ? uC0 : 0;
  const float wl = vC ? Wlin[uC] : 0.f;
  const float bl = blin[0];
  const int wkt = uC >> 5;                    // h-frag write address for (uC,bq)
  const int wln = bq + 16 * ((uC >> 3) & 3);
  const int wj  = uC & 7;

  float c1 = 0.f, c2 = 0.f;
  const f32x4 zf = {0.f, 0.f, 0.f, 0.f};

  __syncthreads();
  // x(0) into stale-parity h1 buffer, k-slot 51 (kt=1 -> lane n+32, j=3)
  if (tid < NB) {
    float x0 = xs[0][tid];
    f16 xh = (f16)x0;
    Bh1[1][0][1][tid + 32][3] = xh;
    Bh1[1][1][1][tid + 32][3] = (f16)(x0 - (float)xh);
  }
  __syncthreads();

  #pragma unroll 1
  for (int t = 0; t < TTOT; ++t) {
    const int pw = t & 1, pr = pw ^ 1;

    // ============ phase 1: layer 1 only (reads Bh1[pr], incl. x at k=51) ============
    const f16x8 b1h0 = *(const f16x8*)&Bh1[pr][0][0][lane][0];
    const f16x8 b1h1 = *(const f16x8*)&Bh1[pr][0][1][lane][0];
    const f16x8 b1l0 = *(const f16x8*)&Bh1[pr][1][0][lane][0];
    const f16x8 b1l1 = *(const f16x8*)&Bh1[pr][1][1][lane][0];

    f32x4 ac1[2];
    #pragma unroll
    for (int m = 0; m < 2; ++m) {
      f32x4 hiC = MFMA(A1[m][0], b1h0, bias1[m], 0, 0, 0);
      hiC = MFMA(A1[m][1], b1h1, hiC, 0, 0, 0);
      f32x4 loC = MFMA(A1[m][0], b1l0, zf, 0, 0, 0);
      loC = MFMA(A1[m][1], b1l1, loC, 0, 0, 0);
      ac1[m] = hiC + loC;
    }

    // xor-8 exchange -> 1 cell per lane
    float q0, q1, q2, q3;
    {
      float e0 = __shfl_xor(ac1[1][0], 8, 64);
      float e1 = __shfl_xor(ac1[1][1], 8, 64);
      float e2 = __shfl_xor(ac1[1][2], 8, 64);
      float e3 = __shfl_xor(ac1[1][3], 8, 64);
      q0 = mhi ? e0 : ac1[0][0];
      q1 = mhi ? e1 : ac1[0][1];
      q2 = mhi ? e2 : ac1[0][2];
      q3 = mhi ? e3 : ac1[0][3];
    }
    {
      float iv = sigf(q0), fv = sigf(q1);
      float gv = tanhf_(q2), ov = sigf(q3);
      c1 = fmaf(fv, c1, iv * gv);
      float h1n = ov * tanhf_(c1);
      if (vC) {
        f16 hh = (f16)h1n;
        Bh1[pw][0][wkt][wln][wj] = hh;
        Bh1[pw][1][wkt][wln][wj] = (f16)(h1n - (float)hh);
      }
    }
    // x(t+1) from input, written pre-barrier (slot 51 disjoint from h-slots;
    // phase-2 reads of slot 51 hit a zero column in A2)
    if (t + 1 < TSEEN && tid < NB) {
      float xn = xs[t + 1][tid];
      f16 xh = (f16)xn;
      Bh1[pw][0][1][tid + 32][3] = xh;
      Bh1[pw][1][1][tid + 32][3] = (f16)(xn - (float)xh);
    }
    __syncthreads();   // barrier A — the only per-step barrier (seen phase)

    // deferred output: out(t-1) for t-1 in [0, 254]
    if (t >= 1 && t < TSEEN && tid < NB) {
      float s = bl;
      #pragma unroll
      for (int w = 0; w < NWAVE; ++w) s += parts[pr][w][tid];
      out[(size_t)(baseb + tid) * TTOT + (t - 1)] = s;
    }

    // ============ phase 2: layer 2 (hh from Bh2[pr], ih from fresh Bh1[pw]) ============
    const f16x8 b2h0 = *(const f16x8*)&Bh2[pr][0][0][lane][0];
    const f16x8 b2h1 = *(const f16x8*)&Bh2[pr][0][1][lane][0];
    const f16x8 b2l0 = *(const f16x8*)&Bh2[pr][1][0][lane][0];
    const f16x8 b2l1 = *(const f16x8*)&Bh2[pr][1][1][lane][0];
    const f16x8 f1h0 = *(const f16x8*)&Bh1[pw][0][0][lane][0];
    const f16x8 f1h1 = *(const f16x8*)&Bh1[pw][0][1][lane][0];
    const f16x8 f1l0 = *(const f16x8*)&Bh1[pw][1][0][lane][0];
    const f16x8 f1l1 = *(const f16x8*)&Bh1[pw][1][1][lane][0];

    f32x4 ac2[2];
    #pragma unroll
    for (int m = 0; m < 2; ++m) {
      f32x4 rA = MFMA(A3[m][0], b2h0, bias2[m], 0, 0, 0);
      rA = MFMA(A3[m][1], b2h1, rA, 0, 0, 0);
      f32x4 rB = MFMA(A3[m][0], b2l0, zf, 0, 0, 0);
      rB = MFMA(A3[m][1], b2l1, rB, 0, 0, 0);
      f32x4 rC = MFMA(A2[m][0], f1h0, zf, 0, 0, 0);
      rC = MFMA(A2[m][1], f1h1, rC, 0, 0, 0);
      f32x4 rD = MFMA(A2[m][0], f1l0, zf, 0, 0, 0);
      rD = MFMA(A2[m][1], f1l1, rD, 0, 0, 0);
      ac2[m] = (rA + rB) + (rC + rD);
    }

    // exchange + cell + head
    {
      float e0 = __shfl_xor(ac2[1][0], 8, 64);
      float e1 = __shfl_xor(ac2[1][1], 8, 64);
      float e2 = __shfl_xor(ac2[1][2], 8, 64);
      float e3 = __shfl_xor(ac2[1][3], 8, 64);
      q0 = mhi ? e0 : ac2[0][0];
      q1 = mhi ? e1 : ac2[0][1];
      q2 = mhi ? e2 : ac2[0][2];
      q3 = mhi ? e3 : ac2[0][3];
    }
    float pv;
    {
      float iv = sigf(q0), fv = sigf(q1);
      float gv = tanhf_(q2), ov = sigf(q3);
      c2 = fmaf(fv, c2, iv * gv);
      float h2n = ov * tanhf_(c2);
      pv = wl * h2n;
      if (vC) {
        f16 hh = (f16)h2n;
        Bh2[pw][0][wkt][wln][wj] = hh;
        Bh2[pw][1][wkt][wln][wj] = (f16)(h2n - (float)hh);
      }
    }
    // butterfly over unit slots: xor 8 (m-half), 16/32 (g4)
    pv += __shfl_xor(pv, 8, 64);
    pv += __shfl_xor(pv, 16, 64);
    pv += __shfl_xor(pv, 32, 64);
    if (lane < NB) parts[pw][wv][lane] = pv;

    // feedback phase: x(t+1) = out(t); also emit outs 255..271
    if (t >= TSEEN - 1) {
      __syncthreads();   // publish parts[pw]
      if (tid < NB) {
        float fbv = bl;
        #pragma unroll
        for (int w = 0; w < NWAVE; ++w) fbv += parts[pw][w][tid];
        out[(size_t)(baseb + tid) * TTOT + t] = fbv;
        if (t < TTOT - 1) {
          f16 xh = (f16)fbv;
          Bh1[pw][0][1][tid + 32][3] = xh;
          Bh1[pw][1][1][tid + 32][3] = (f16)(fbv - (float)xh);
        }
      }
      __syncthreads();   // protect slot-51 write from next-iter reads
    }
  }
}

extern "C" void kernel_launch(void* const* d_in, const int* in_sizes, int n_in,
                              void* d_out, int out_size, void* d_ws, size_t ws_size,
                              hipStream_t stream) {
  (void)in_sizes; (void)n_in; (void)d_ws; (void)ws_size; (void)out_size;
  const float* inp  = (const float*)d_in[0];
  const float* Wih1 = (const float*)d_in[1];
  const float* bih1 = (const float*)d_in[2];
  const float* Whh1 = (const float*)d_in[3];
  const float* bhh1 = (const float*)d_in[4];
  const float* Wih2 = (const float*)d_in[5];
  const float* bih2 = (const float*)d_in[6];
  const float* Whh2 = (const float*)d_in[7];
  const float* bhh2 = (const float*)d_in[8];
  const float* Wlin = (const float*)d_in[9];
  const float* blin = (const float*)d_in[10];
  float* outp = (float*)d_out;

  lstm2_kernel<<<NBLOCKS, THREADS, 0, stream>>>(
      inp, Wih1, bih1, Whh1, bhh1, Wih2, bih2, Whh2, bhh2, Wlin, blin, outp);
}